// Round 5
// baseline (1769.068 us; speedup 1.0000x reference)
//
#include <hip/hip_runtime.h>
#include <math.h>
#include <stdint.h>

typedef unsigned short u16;
typedef __attribute__((ext_vector_type(8))) short bf8;      // 8 bf16 MFMA operand (4 VGPR)
typedef __attribute__((ext_vector_type(8))) unsigned short us8;
typedef __attribute__((ext_vector_type(4))) float f4;

#define B_  32
#define T_  577
#define D_  768
#define BT  18464
#define H3  2304
#define HD  3072
#define NH  12
#define DH  64
#define TT  332929ull        // T_*T_
#define TP  608              // T_ padded to mult of 32 (K dim of AV)
#define LNEPS 1e-6f

// async global->LDS, 16B per lane; dest = wave-uniform base + lane*16
#define GLOAD_LDS16(gp, lp)                                                \
  __builtin_amdgcn_global_load_lds(                                       \
      (const __attribute__((address_space(1))) void*)(gp),                 \
      (__attribute__((address_space(3))) void*)(unsigned)(uintptr_t)(lp),  \
      16, 0, 0)

__device__ __forceinline__ u16 f2bf(float f) {
  unsigned int u = __float_as_uint(f);
  u += 0x7fffu + ((u >> 16) & 1u);       // round-to-nearest-even
  return (u16)(u >> 16);
}

// ---------------- LayerNorm fp32 -> bf16 ----------------
__global__ __launch_bounds__(256) void ln_bf16(const float* __restrict__ x,
    const float* __restrict__ w, const float* __restrict__ b, u16* __restrict__ y) {
  int row = blockIdx.x;
  const float* xr = x + (size_t)row * D_;
  int t = threadIdx.x;
  float v0 = xr[t], v1 = xr[t + 256], v2 = xr[t + 512];
  float s  = v0 + v1 + v2;
  float ss = v0*v0 + v1*v1 + v2*v2;
  #pragma unroll
  for (int o = 32; o >= 1; o >>= 1) {
    s  += __shfl_xor(s,  o, 64);
    ss += __shfl_xor(ss, o, 64);
  }
  __shared__ float rs_[4], rss_[4];
  int wid = t >> 6;
  if ((t & 63) == 0) { rs_[wid] = s; rss_[wid] = ss; }
  __syncthreads();
  s  = rs_[0]  + rs_[1]  + rs_[2]  + rs_[3];
  ss = rss_[0] + rss_[1] + rss_[2] + rss_[3];
  float mu  = s * (1.0f / D_);
  float var = ss * (1.0f / D_) - mu * mu;
  float rstd = rsqrtf(var + LNEPS);
  u16* yr = y + (size_t)row * D_;
  yr[t]       = f2bf((v0 - mu) * rstd * w[t]       + b[t]);
  yr[t + 256] = f2bf((v1 - mu) * rstd * w[t + 256] + b[t + 256]);
  yr[t + 512] = f2bf((v2 - mu) * rstd * w[t + 512] + b[t + 512]);
}

// ---------------- weight fp32 [K,N] -> bf16 transposed [N,K] ----------------
__global__ __launch_bounds__(256) void wconv(const float* __restrict__ W,
    u16* __restrict__ Wt, int K, int N) {
  __shared__ float tile[64][68];
  int n0 = blockIdx.x * 64, k0 = blockIdx.y * 64;
  int t = threadIdx.x;
  #pragma unroll
  for (int r = 0; r < 4; ++r) {
    int flat = r * 256 + t;
    int kr = flat >> 4, g = flat & 15;
    float4 v = *(const float4*)(W + (size_t)(k0 + kr) * N + n0 + g * 4);
    *(float4*)&tile[kr][g * 4] = v;
  }
  __syncthreads();
  #pragma unroll
  for (int r = 0; r < 2; ++r) {
    int flat = r * 256 + t;
    int n = flat >> 3, g2 = flat & 7;
    us8 o;
    #pragma unroll
    for (int j = 0; j < 8; ++j) o[j] = f2bf(tile[g2 * 8 + j][n]);
    *(us8*)(Wt + (size_t)(n0 + n) * K + k0 + g2 * 8) = o;
  }
}

// ---------------- build Vt [z][128][TP] from qkv chunk V-slot ----------------
__global__ __launch_bounds__(256) void vt_prep(const u16* __restrict__ qkvc,
    u16* __restrict__ Vt) {
  int z = blockIdx.z;
  int bb = z / NH, h = z - bb * NH;
  u16* out = Vt + (size_t)z * 128 * TP;
  int k0 = blockIdx.x * 64;
  int t = threadIdx.x;
  if (blockIdx.y == 1) {
    #pragma unroll
    for (int r = 0; r < 2; ++r) {
      int flat = r * 256 + t;
      int n = 64 + (flat >> 3), g = flat & 7;
      int kc = k0 + g * 8;
      if (kc < TP) {
        us8 zz = {0,0,0,0,0,0,0,0};
        *(us8*)(out + (size_t)n * TP + kc) = zz;
      }
    }
    return;
  }
  __shared__ u16 tile[64][72];
  const u16* src = qkvc + ((size_t)bb * T_) * H3 + 2 * D_ + h * DH;
  #pragma unroll
  for (int r = 0; r < 2; ++r) {
    int flat = r * 256 + t;
    int kr = flat >> 3, g = flat & 7;
    int gk = k0 + kr;
    us8 v = {0,0,0,0,0,0,0,0};
    if (gk < T_) v = *(const us8*)(src + (size_t)gk * H3 + g * 8);
    *(us8*)&tile[kr][g * 8] = v;
  }
  __syncthreads();
  #pragma unroll
  for (int r = 0; r < 2; ++r) {
    int flat = r * 256 + t;
    int n = flat >> 3, g2 = flat & 7;
    int kc = k0 + g2 * 8;
    if (kc < TP) {
      us8 o;
      #pragma unroll
      for (int j = 0; j < 8; ++j) o[j] = tile[g2 * 8 + j][n];
      *(us8*)(out + (size_t)n * TP + kc) = o;
    }
  }
}

// ---------------- softmax over heads; fp32 dp -> bf16 P (padded to TP) ----------------
__global__ __launch_bounds__(256) void softmax_pad(const float* __restrict__ dp,
    u16* __restrict__ P) {
  int bb = blockIdx.y;
  int i = blockIdx.x * 256 + threadIdx.x;
  if (i >= T_ * TP) return;
  int qq = i / TP, kp = i - qq * TP;
  u16* Pb = P + (size_t)bb * NH * T_ * TP + (size_t)qq * TP + kp;
  if (kp >= T_) {
    #pragma unroll
    for (int h = 0; h < NH; ++h) Pb[(size_t)h * T_ * TP] = 0;
    return;
  }
  const float* db = dp + (size_t)bb * NH * TT + (size_t)qq * T_ + kp;
  float v[NH];
  float m = -1e30f;
  #pragma unroll
  for (int h = 0; h < NH; ++h) { v[h] = db[(size_t)h * TT]; m = fmaxf(m, v[h]); }
  float s = 0.f;
  #pragma unroll
  for (int h = 0; h < NH; ++h) { v[h] = __expf(v[h] - m); s += v[h]; }
  float inv = 1.0f / s;
  #pragma unroll
  for (int h = 0; h < NH; ++h) Pb[(size_t)h * T_ * TP] = f2bf(v[h] * inv);
}

// ---------------- bf16 MFMA GEMM: C = epi(A[M,K] @ Bt[N,K]^T) ----------------
// 128x128 tile, BK=32, 16x16x32 MFMA, 4 waves each 64x64, global_load_lds staging.
// K-major LDS layout [kgroup][row] -> conflict-free ds_read_b128 fragment loads.
// EPI: 0 = bias -> bf16 C        1 = bias+res -> f32 C
//      2 = bias+gelu -> bf16 C   3 = *scale -> f32 C      4 = plain -> bf16 C
template <int EPI>
__global__ __launch_bounds__(256) void gemm_bf16(
    const u16* __restrict__ Abase, int lda,
    const u16* __restrict__ Bbase, int ldb,
    const float* __restrict__ bias,
    const float* __restrict__ res, int ldr,
    float* __restrict__ Cf, u16* __restrict__ Cb, int ldc,
    int M, int Nst, int Nb, int K, float scale, int bmode) {
  __shared__ u16 As[4096];   // [kg 0..3][row 0..127][8]
  __shared__ u16 Bs[4096];
  int z = blockIdx.z;
  size_t aoff = 0, boff = 0, coff = 0;
  if (bmode == 1) {
    int bb = z / NH, h = z - bb * NH;
    aoff = (size_t)bb * T_ * H3 + (size_t)h * DH;
    boff = aoff + D_;
    coff = (size_t)z * TT;
  } else if (bmode == 2) {
    int bb = z / NH, h = z - bb * NH;
    aoff = (size_t)z * T_ * TP;
    boff = (size_t)z * 128 * TP;
    coff = (size_t)bb * T_ * H3 + (size_t)h * DH;
  }
  const u16* A  = Abase + aoff;
  const u16* Bt = Bbase + boff;

  // XCD-aware swizzle for the big GEMMs: contiguous flat-id range per XCD.
  int bx = blockIdx.x, by = blockIdx.y;
  if (bmode == 0) {
    int gx = gridDim.x;
    int g  = gx * gridDim.y;
    int i  = by * gx + bx;
    int chunk = g >> 3, rem = g & 7;
    int xcd = i & 7, loc = i >> 3;
    int start = xcd * chunk + (xcd < rem ? xcd : rem);
    int o = start + loc;
    by = o / gx; bx = o - by * gx;
  }
  int m_base = by * 128, n_base = bx * 128;

  int tid = threadIdx.x;
  int wid = tid >> 6, lane = tid & 63;
  int wm = (wid >> 1) * 64, wn = (wid & 1) * 64;
  int lm = lane & 15, q = lane >> 4;

  // staging map: thread -> (row = tid&127, kgroup = tid>>7 and +2 on 2nd issue)
  int srow = tid & 127;
  int skg  = tid >> 7;
  int gm = m_base + srow; gm = gm < M ? gm : M - 1;
  int gn = n_base + srow; gn = gn < Nb ? gn : Nb - 1;
  const u16* aP = A  + (size_t)gm * lda + skg * 8;
  const u16* bP = Bt + (size_t)gn * ldb + skg * 8;
  u16* dA = As + (skg * 128 + srow) * 8;   // == wave-uniform base + lane*16B
  u16* dB = Bs + (skg * 128 + srow) * 8;

  f4 acc[4][4] = {};

  for (int kc = 0; kc < K; kc += 32) {
    GLOAD_LDS16(aP + kc, dA);
    GLOAD_LDS16(aP + kc + 16, dA + 2048);
    GLOAD_LDS16(bP + kc, dB);
    GLOAD_LDS16(bP + kc + 16, dB + 2048);
    __syncthreads();
    bf8 af[4], bfr[4];
    #pragma unroll
    for (int mt = 0; mt < 4; ++mt)
      af[mt] = *(const bf8*)&As[(q * 128 + wm + mt * 16 + lm) * 8];
    #pragma unroll
    for (int nt = 0; nt < 4; ++nt)
      bfr[nt] = *(const bf8*)&Bs[(q * 128 + wn + nt * 16 + lm) * 8];
    #pragma unroll
    for (int mt = 0; mt < 4; ++mt)
      #pragma unroll
      for (int nt = 0; nt < 4; ++nt)
        acc[mt][nt] = __builtin_amdgcn_mfma_f32_16x16x32_bf16(af[mt], bfr[nt], acc[mt][nt], 0, 0, 0);
    __syncthreads();
  }

  // epilogue: C/D layout col = lane&15, row = quad*4 + reg
  #pragma unroll
  for (int mt = 0; mt < 4; ++mt) {
    #pragma unroll
    for (int i = 0; i < 4; ++i) {
      int grow = m_base + wm + mt * 16 + q * 4 + i;
      if (grow >= M) continue;
      #pragma unroll
      for (int nt = 0; nt < 4; ++nt) {
        int gcol = n_base + wn + nt * 16 + lm;
        if (gcol >= Nst) continue;
        float v = acc[mt][nt][i];
        if (EPI == 0) {
          v += bias[gcol];
          Cb[coff + (size_t)grow * ldc + gcol] = f2bf(v);
        } else if (EPI == 1) {
          v += bias[gcol] + res[(size_t)grow * ldr + gcol];
          Cf[(size_t)grow * ldc + gcol] = v;
        } else if (EPI == 2) {
          v += bias[gcol];
          // gelu tanh-form: v * sigmoid(2*(0.79788456*v + 0.03567741*v^3))
          float t = v * fmaf(v * v, -0.0713548163f, -1.5957691216f);
          v = __fdividef(v, 1.0f + __expf(t));
          Cb[coff + (size_t)grow * ldc + gcol] = f2bf(v);
        } else if (EPI == 3) {
          Cf[coff + (size_t)grow * ldc + gcol] = v * scale;
        } else {
          Cb[coff + (size_t)grow * ldc + gcol] = f2bf(v);
        }
      }
    }
  }
}

// ---------------- launch ----------------
extern "C" void kernel_launch(void* const* d_in, const int* in_sizes, int n_in,
                              void* d_out, int out_size, void* d_ws, size_t ws_size,
                              hipStream_t stream) {
  const float* x     = (const float*)d_in[0];
  const float* ln1w  = (const float*)d_in[1];
  const float* ln1b  = (const float*)d_in[2];
  const float* qkvw  = (const float*)d_in[3];
  const float* qkvb  = (const float*)d_in[4];
  const float* projw = (const float*)d_in[5];
  const float* projb = (const float*)d_in[6];
  const float* ln2w  = (const float*)d_in[7];
  const float* ln2b  = (const float*)d_in[8];
  const float* fc1w  = (const float*)d_in[9];
  const float* fc1b  = (const float*)d_in[10];
  const float* fc2w  = (const float*)d_in[11];
  const float* fc2b  = (const float*)d_in[12];
  float* out = (float*)d_out;

  // ---- workspace layout (ws >= 404 MB proven in round 2) ----
  u16* qkvwT  = (u16*)d_ws;                       // [2304][768]
  u16* projwT = qkvwT  + (size_t)H3 * D_;         // [768][768]
  u16* fc1wT  = projwT + (size_t)D_ * D_;         // [3072][768]
  u16* fc2wT  = fc1wT  + (size_t)HD * D_;         // [768][3072]
  u16* ybf    = fc2wT  + (size_t)D_ * HD;         // [BT][768]   28.4 MB
  u16* qkvbf  = ybf    + (size_t)BT * D_;         // [BT][2304]  85 MB
  char* scratch = (char*)(qkvbf + (size_t)BT * H3);
  size_t used = (size_t)(scratch - (char*)d_ws);
  size_t avail = ws_size - used;

  // attention scratch per batch: dp fp32 + P bf16 + Vt bf16
  const size_t per_batch = (size_t)NH * TT * 4 + (size_t)NH * T_ * TP * 2 +
                           (size_t)NH * 128 * TP * 2;
  int NBA = (int)(avail / per_batch);
  if (NBA < 1) NBA = 1;
  if (NBA > 4) NBA = 4;      // keep dp/P/Vt L3-resident (~105 MB at 4)

  float* dp = (float*)scratch;
  u16*   P  = (u16*)(dp + (size_t)NBA * NH * TT);
  u16*   Vt = P + (size_t)NBA * NH * T_ * TP;

  // ---- weights: fp32 [K,N] -> bf16 [N,K] ----
  wconv<<<dim3(H3 / 64, D_ / 64), 256, 0, stream>>>(qkvw, qkvwT, D_, H3);
  wconv<<<dim3(D_ / 64, D_ / 64), 256, 0, stream>>>(projw, projwT, D_, D_);
  wconv<<<dim3(HD / 64, D_ / 64), 256, 0, stream>>>(fc1w, fc1wT, D_, HD);
  wconv<<<dim3(D_ / 64, HD / 64), 256, 0, stream>>>(fc2w, fc2wT, HD, D_);

  // ---- attention branch ----
  ln_bf16<<<BT, 256, 0, stream>>>(x, ln1w, ln1b, ybf);
  gemm_bf16<0><<<dim3(H3 / 128, (BT + 127) / 128), 256, 0, stream>>>(
      ybf, D_, qkvwT, D_, qkvb, nullptr, 0, nullptr, qkvbf, H3,
      BT, H3, H3, D_, 1.f, 0);

  for (int b0 = 0; b0 < B_; b0 += NBA) {
    int nb = (B_ - b0 < NBA) ? (B_ - b0) : NBA;
    u16* qkvc = qkvbf + (size_t)b0 * T_ * H3;
    vt_prep<<<dim3(10, 2, nb * NH), 256, 0, stream>>>(qkvc, Vt);
    gemm_bf16<3><<<dim3(5, 5, nb * NH), 256, 0, stream>>>(
        qkvc, H3, qkvc, H3, nullptr, nullptr, 0, dp, nullptr, T_,
        T_, T_, T_, DH, 0.125f, 1);
    softmax_pad<<<dim3((T_ * TP + 255) / 256, nb), 256, 0, stream>>>(dp, P);
    gemm_bf16<4><<<dim3(1, 5, nb * NH), 256, 0, stream>>>(
        P, TP, Vt, TP, nullptr, nullptr, 0, nullptr, qkvc, H3,
        T_, DH, 128, TP, 1.f, 2);
  }
  // proj: A = wa living in Q slots of qkvbf (lda = 3D); out = x + wa@W
  gemm_bf16<1><<<dim3(D_ / 128, (BT + 127) / 128), 256, 0, stream>>>(
      qkvbf, H3, projwT, D_, projb, x, D_, out, nullptr, D_,
      BT, D_, D_, D_, 1.f, 0);

  // ---- MLP branch: full LN, then row-chunked fc1/fc2 for L3-resident hdn ----
  ln_bf16<<<BT, 256, 0, stream>>>(out, ln2w, ln2b, ybf);
  size_t chrows = avail / ((size_t)HD * 2);
  int CH = (chrows > 6144) ? 6144 : (int)chrows;
  CH &= ~127;
  if (CH < 128) CH = 128;
  u16* hdn = (u16*)scratch;
  for (int r0 = 0; r0 < BT; r0 += CH) {
    int rows = (BT - r0 < CH) ? (BT - r0) : CH;
    float* oc = out + (size_t)r0 * D_;
    gemm_bf16<2><<<dim3(HD / 128, (rows + 127) / 128), 256, 0, stream>>>(
        ybf + (size_t)r0 * D_, D_, fc1wT, D_, fc1b, nullptr, 0, nullptr, hdn, HD,
        rows, HD, HD, D_, 1.f, 0);
    gemm_bf16<1><<<dim3(D_ / 128, (rows + 127) / 128), 256, 0, stream>>>(
        hdn, HD, fc2wT, HD, fc2b, oc, D_, oc, nullptr, D_,
        rows, D_, D_, HD, 1.f, 0);
  }
}

// Round 6
// 1703.420 us; speedup vs baseline: 1.0385x; 1.0385x over previous
//
#include <hip/hip_runtime.h>
#include <math.h>
#include <stdint.h>

typedef unsigned short u16;
typedef __attribute__((ext_vector_type(8))) short bf8;      // 8 bf16 MFMA operand (4 VGPR)
typedef __attribute__((ext_vector_type(8))) unsigned short us8;
typedef __attribute__((ext_vector_type(4))) float f4;

#define B_  32
#define T_  577
#define D_  768
#define BT  18464
#define H3  2304
#define HD  3072
#define NH  12
#define DH  64
#define TT  332929ull        // T_*T_
#define TP  608              // T_ padded to mult of 32 (K dim of AV)
#define LNEPS 1e-6f

// async global->LDS, 16B per lane; dest = wave-uniform base + lane*16
#define GLOAD_LDS16(gp, lp)                                                \
  __builtin_amdgcn_global_load_lds(                                       \
      (const __attribute__((address_space(1))) void*)(gp),                 \
      (__attribute__((address_space(3))) void*)(unsigned)(uintptr_t)(lp),  \
      16, 0, 0)

__device__ __forceinline__ u16 f2bf(float f) {
  unsigned int u = __float_as_uint(f);
  u += 0x7fffu + ((u >> 16) & 1u);       // round-to-nearest-even
  return (u16)(u >> 16);
}
__device__ __forceinline__ float bf2f(u16 v) {
  return __uint_as_float(((unsigned)v) << 16);
}

// ---------------- LayerNorm fp32 -> bf16 ----------------
__global__ __launch_bounds__(256) void ln_bf16(const float* __restrict__ x,
    const float* __restrict__ w, const float* __restrict__ b, u16* __restrict__ y) {
  int row = blockIdx.x;
  const float* xr = x + (size_t)row * D_;
  int t = threadIdx.x;
  float v0 = xr[t], v1 = xr[t + 256], v2 = xr[t + 512];
  float s  = v0 + v1 + v2;
  float ss = v0*v0 + v1*v1 + v2*v2;
  #pragma unroll
  for (int o = 32; o >= 1; o >>= 1) {
    s  += __shfl_xor(s,  o, 64);
    ss += __shfl_xor(ss, o, 64);
  }
  __shared__ float rs_[4], rss_[4];
  int wid = t >> 6;
  if ((t & 63) == 0) { rs_[wid] = s; rss_[wid] = ss; }
  __syncthreads();
  s  = rs_[0]  + rs_[1]  + rs_[2]  + rs_[3];
  ss = rss_[0] + rss_[1] + rss_[2] + rss_[3];
  float mu  = s * (1.0f / D_);
  float var = ss * (1.0f / D_) - mu * mu;
  float rstd = rsqrtf(var + LNEPS);
  u16* yr = y + (size_t)row * D_;
  yr[t]       = f2bf((v0 - mu) * rstd * w[t]       + b[t]);
  yr[t + 256] = f2bf((v1 - mu) * rstd * w[t + 256] + b[t + 256]);
  yr[t + 512] = f2bf((v2 - mu) * rstd * w[t + 512] + b[t + 512]);
}

// ---------------- weight fp32 [K,N] -> bf16 transposed [N,K] ----------------
__global__ __launch_bounds__(256) void wconv(const float* __restrict__ W,
    u16* __restrict__ Wt, int K, int N) {
  __shared__ float tile[64][68];
  int n0 = blockIdx.x * 64, k0 = blockIdx.y * 64;
  int t = threadIdx.x;
  #pragma unroll
  for (int r = 0; r < 4; ++r) {
    int flat = r * 256 + t;
    int kr = flat >> 4, g = flat & 15;
    float4 v = *(const float4*)(W + (size_t)(k0 + kr) * N + n0 + g * 4);
    *(float4*)&tile[kr][g * 4] = v;
  }
  __syncthreads();
  #pragma unroll
  for (int r = 0; r < 2; ++r) {
    int flat = r * 256 + t;
    int n = flat >> 3, g2 = flat & 7;
    us8 o;
    #pragma unroll
    for (int j = 0; j < 8; ++j) o[j] = f2bf(tile[g2 * 8 + j][n]);
    *(us8*)(Wt + (size_t)(n0 + n) * K + k0 + g2 * 8) = o;
  }
}

// ---------------- build Vt [z][128][TP] from qkv chunk V-slot ----------------
__global__ __launch_bounds__(256) void vt_prep(const u16* __restrict__ qkvc,
    u16* __restrict__ Vt) {
  int z = blockIdx.z;
  int bb = z / NH, h = z - bb * NH;
  u16* out = Vt + (size_t)z * 128 * TP;
  int k0 = blockIdx.x * 64;
  int t = threadIdx.x;
  if (blockIdx.y == 1) {
    #pragma unroll
    for (int r = 0; r < 2; ++r) {
      int flat = r * 256 + t;
      int n = 64 + (flat >> 3), g = flat & 7;
      int kc = k0 + g * 8;
      if (kc < TP) {
        us8 zz = {0,0,0,0,0,0,0,0};
        *(us8*)(out + (size_t)n * TP + kc) = zz;
      }
    }
    return;
  }
  __shared__ u16 tile[64][72];
  const u16* src = qkvc + ((size_t)bb * T_) * H3 + 2 * D_ + h * DH;
  #pragma unroll
  for (int r = 0; r < 2; ++r) {
    int flat = r * 256 + t;
    int kr = flat >> 3, g = flat & 7;
    int gk = k0 + kr;
    us8 v = {0,0,0,0,0,0,0,0};
    if (gk < T_) v = *(const us8*)(src + (size_t)gk * H3 + g * 8);
    *(us8*)&tile[kr][g * 8] = v;
  }
  __syncthreads();
  #pragma unroll
  for (int r = 0; r < 2; ++r) {
    int flat = r * 256 + t;
    int n = flat >> 3, g2 = flat & 7;
    int kc = k0 + g2 * 8;
    if (kc < TP) {
      us8 o;
      #pragma unroll
      for (int j = 0; j < 8; ++j) o[j] = tile[g2 * 8 + j][n];
      *(us8*)(out + (size_t)n * TP + kc) = o;
    }
  }
}

// ---------------- softmax over heads; bf16 dp -> bf16 P (padded to TP) ----------------
__global__ __launch_bounds__(256) void softmax_pad(const u16* __restrict__ dp,
    u16* __restrict__ P) {
  int bb = blockIdx.y;
  int i = blockIdx.x * 256 + threadIdx.x;
  if (i >= T_ * TP) return;
  int qq = i / TP, kp = i - qq * TP;
  u16* Pb = P + (size_t)bb * NH * T_ * TP + (size_t)qq * TP + kp;
  if (kp >= T_) {
    #pragma unroll
    for (int h = 0; h < NH; ++h) Pb[(size_t)h * T_ * TP] = 0;
    return;
  }
  const u16* db = dp + (size_t)bb * NH * TT + (size_t)qq * T_ + kp;
  float v[NH];
  float m = -1e30f;
  #pragma unroll
  for (int h = 0; h < NH; ++h) { v[h] = bf2f(db[(size_t)h * TT]); m = fmaxf(m, v[h]); }
  float s = 0.f;
  #pragma unroll
  for (int h = 0; h < NH; ++h) { v[h] = __expf(v[h] - m); s += v[h]; }
  float inv = 1.0f / s;
  #pragma unroll
  for (int h = 0; h < NH; ++h) Pb[(size_t)h * T_ * TP] = f2bf(v[h] * inv);
}

// ---------------- bf16 MFMA GEMM: C = epi(A[M,K] @ Bt[N,K]^T) ----------------
// 128x128 tile, BK=32, 16x16x32 MFMA, 4 waves each 64x64, global_load_lds staging.
// K-major LDS layout [kgroup][row] -> conflict-free ds_read_b128 fragment loads.
// EPI: 0 = bias -> bf16 C        1 = bias+res -> f32 C
//      2 = bias+gelu -> bf16 C   3 = *scale -> bf16 C     4 = plain -> bf16 C
template <int EPI>
__global__ __launch_bounds__(256) void gemm_bf16(
    const u16* __restrict__ Abase, int lda,
    const u16* __restrict__ Bbase, int ldb,
    const float* __restrict__ bias,
    const float* __restrict__ res, int ldr,
    float* __restrict__ Cf, u16* __restrict__ Cb, int ldc,
    int M, int Nst, int Nb, int K, float scale, int bmode) {
  __shared__ u16 As[4096];   // [kg 0..3][row 0..127][8]
  __shared__ u16 Bs[4096];
  int z = blockIdx.z;
  size_t aoff = 0, boff = 0, coff = 0;
  if (bmode == 1) {
    int bb = z / NH, h = z - bb * NH;
    aoff = (size_t)bb * T_ * H3 + (size_t)h * DH;
    boff = aoff + D_;
    coff = (size_t)z * TT;
  } else if (bmode == 2) {
    int bb = z / NH, h = z - bb * NH;
    aoff = (size_t)z * T_ * TP;
    boff = (size_t)z * 128 * TP;
    coff = (size_t)bb * T_ * H3 + (size_t)h * DH;
  }
  const u16* A  = Abase + aoff;
  const u16* Bt = Bbase + boff;

  // XCD-aware swizzle for the big GEMMs: contiguous flat-id range per XCD.
  int bx = blockIdx.x, by = blockIdx.y;
  if (bmode == 0) {
    int gx = gridDim.x;
    int g  = gx * gridDim.y;
    int i  = by * gx + bx;
    int chunk = g >> 3, rem = g & 7;
    int xcd = i & 7, loc = i >> 3;
    int start = xcd * chunk + (xcd < rem ? xcd : rem);
    int o = start + loc;
    by = o / gx; bx = o - by * gx;
  }
  int m_base = by * 128, n_base = bx * 128;

  int tid = threadIdx.x;
  int wid = tid >> 6, lane = tid & 63;
  int wm = (wid >> 1) * 64, wn = (wid & 1) * 64;
  int lm = lane & 15, q = lane >> 4;

  // staging map: thread -> (row = tid&127, kgroup = tid>>7, +2 on 2nd issue)
  int srow = tid & 127;
  int skg  = tid >> 7;
  int gm = m_base + srow; gm = gm < M ? gm : M - 1;
  int gn = n_base + srow; gn = gn < Nb ? gn : Nb - 1;
  const u16* aP = A  + (size_t)gm * lda + skg * 8;
  const u16* bP = Bt + (size_t)gn * ldb + skg * 8;
  u16* dA = As + (skg * 128 + srow) * 8;   // == wave-uniform base + lane*16B
  u16* dB = Bs + (skg * 128 + srow) * 8;

  f4 acc[4][4] = {};

  for (int kc = 0; kc < K; kc += 32) {
    GLOAD_LDS16(aP + kc, dA);
    GLOAD_LDS16(aP + kc + 16, dA + 2048);
    GLOAD_LDS16(bP + kc, dB);
    GLOAD_LDS16(bP + kc + 16, dB + 2048);
    __syncthreads();
    bf8 af[4], bfr[4];
    #pragma unroll
    for (int mt = 0; mt < 4; ++mt)
      af[mt] = *(const bf8*)&As[(q * 128 + wm + mt * 16 + lm) * 8];
    #pragma unroll
    for (int nt = 0; nt < 4; ++nt)
      bfr[nt] = *(const bf8*)&Bs[(q * 128 + wn + nt * 16 + lm) * 8];
    #pragma unroll
    for (int mt = 0; mt < 4; ++mt)
      #pragma unroll
      for (int nt = 0; nt < 4; ++nt)
        acc[mt][nt] = __builtin_amdgcn_mfma_f32_16x16x32_bf16(af[mt], bfr[nt], acc[mt][nt], 0, 0, 0);
    __syncthreads();
  }

  // epilogue: C/D layout col = lane&15, row = quad*4 + reg
  #pragma unroll
  for (int mt = 0; mt < 4; ++mt) {
    #pragma unroll
    for (int i = 0; i < 4; ++i) {
      int grow = m_base + wm + mt * 16 + q * 4 + i;
      if (grow >= M) continue;
      #pragma unroll
      for (int nt = 0; nt < 4; ++nt) {
        int gcol = n_base + wn + nt * 16 + lm;
        if (gcol >= Nst) continue;
        float v = acc[mt][nt][i];
        if (EPI == 0) {
          v += bias[gcol];
          Cb[coff + (size_t)grow * ldc + gcol] = f2bf(v);
        } else if (EPI == 1) {
          v += bias[gcol] + res[(size_t)grow * ldr + gcol];
          Cf[(size_t)grow * ldc + gcol] = v;
        } else if (EPI == 2) {
          v += bias[gcol];
          // gelu tanh-form
          float t = v * fmaf(v * v, -0.0713548163f, -1.5957691216f);
          v = __fdividef(v, 1.0f + __expf(t));
          Cb[coff + (size_t)grow * ldc + gcol] = f2bf(v);
        } else if (EPI == 3) {
          Cb[coff + (size_t)grow * ldc + gcol] = f2bf(v * scale);
        } else {
          Cb[coff + (size_t)grow * ldc + gcol] = f2bf(v);
        }
      }
    }
  }
}

// ---------------- launch ----------------
extern "C" void kernel_launch(void* const* d_in, const int* in_sizes, int n_in,
                              void* d_out, int out_size, void* d_ws, size_t ws_size,
                              hipStream_t stream) {
  const float* x     = (const float*)d_in[0];
  const float* ln1w  = (const float*)d_in[1];
  const float* ln1b  = (const float*)d_in[2];
  const float* qkvw  = (const float*)d_in[3];
  const float* qkvb  = (const float*)d_in[4];
  const float* projw = (const float*)d_in[5];
  const float* projb = (const float*)d_in[6];
  const float* ln2w  = (const float*)d_in[7];
  const float* ln2b  = (const float*)d_in[8];
  const float* fc1w  = (const float*)d_in[9];
  const float* fc1b  = (const float*)d_in[10];
  const float* fc2w  = (const float*)d_in[11];
  const float* fc2b  = (const float*)d_in[12];
  float* out = (float*)d_out;

  // ---- workspace layout (ws ~740+ MB inferred from rounds 2/4 dispatch counts) ----
  u16* qkvwT  = (u16*)d_ws;                       // [2304][768]
  u16* projwT = qkvwT  + (size_t)H3 * D_;         // [768][768]
  u16* fc1wT  = projwT + (size_t)D_ * D_;         // [3072][768]
  u16* fc2wT  = fc1wT  + (size_t)HD * D_;         // [768][3072]
  u16* ybf    = fc2wT  + (size_t)D_ * HD;         // [BT][768]   28.4 MB
  u16* qkvbf  = ybf    + (size_t)BT * D_;         // [BT][2304]  85 MB
  char* scratch = (char*)(qkvbf + (size_t)BT * H3);
  size_t used = (size_t)(scratch - (char*)d_ws);
  size_t avail = ws_size > used ? ws_size - used : 0;

  // attention scratch per batch: dp bf16 + P bf16 + Vt bf16 (~18.3 MB)
  const size_t per_batch = (size_t)NH * TT * 2 + (size_t)NH * T_ * TP * 2 +
                           (size_t)NH * 128 * TP * 2;
  int NBA = (int)(avail / per_batch);
  if (NBA < 1)  NBA = 1;
  if (NBA > B_) NBA = B_;

  u16* dp = (u16*)scratch;
  u16* P  = dp + (size_t)NBA * NH * TT;
  u16* Vt = P + (size_t)NBA * NH * T_ * TP;

  // ---- weights: fp32 [K,N] -> bf16 [N,K] ----
  wconv<<<dim3(H3 / 64, D_ / 64), 256, 0, stream>>>(qkvw, qkvwT, D_, H3);
  wconv<<<dim3(D_ / 64, D_ / 64), 256, 0, stream>>>(projw, projwT, D_, D_);
  wconv<<<dim3(HD / 64, D_ / 64), 256, 0, stream>>>(fc1w, fc1wT, D_, HD);
  wconv<<<dim3(D_ / 64, HD / 64), 256, 0, stream>>>(fc2w, fc2wT, HD, D_);

  // ---- attention branch ----
  ln_bf16<<<BT, 256, 0, stream>>>(x, ln1w, ln1b, ybf);
  gemm_bf16<0><<<dim3(H3 / 128, (BT + 127) / 128), 256, 0, stream>>>(
      ybf, D_, qkvwT, D_, qkvb, nullptr, 0, nullptr, qkvbf, H3,
      BT, H3, H3, D_, 1.f, 0);

  for (int b0 = 0; b0 < B_; b0 += NBA) {
    int nb = (B_ - b0 < NBA) ? (B_ - b0) : NBA;
    u16* qkvc = qkvbf + (size_t)b0 * T_ * H3;
    vt_prep<<<dim3(10, 2, nb * NH), 256, 0, stream>>>(qkvc, Vt);
    gemm_bf16<3><<<dim3(5, 5, nb * NH), 256, 0, stream>>>(
        qkvc, H3, qkvc, H3, nullptr, nullptr, 0, nullptr, dp, T_,
        T_, T_, T_, DH, 0.125f, 1);
    softmax_pad<<<dim3((T_ * TP + 255) / 256, nb), 256, 0, stream>>>(dp, P);
    gemm_bf16<4><<<dim3(1, 5, nb * NH), 256, 0, stream>>>(
        P, TP, Vt, TP, nullptr, nullptr, 0, nullptr, qkvc, H3,
        T_, DH, 128, TP, 1.f, 2);
  }
  // proj: A = wa living in Q slots of qkvbf (lda = 3D); out = x + wa@W
  gemm_bf16<1><<<dim3(D_ / 128, (BT + 127) / 128), 256, 0, stream>>>(
      qkvbf, H3, projwT, D_, projb, x, D_, out, nullptr, D_,
      BT, D_, D_, D_, 1.f, 0);

  // ---- MLP branch: full LN, then 4 balanced row-chunks (hdn L3-resident) ----
  ln_bf16<<<BT, 256, 0, stream>>>(out, ln2w, ln2b, ybf);
  int CH = 4616;                                   // BT/4 exactly
  {
    size_t maxch = avail / ((size_t)HD * 2);
    if ((size_t)CH > maxch) {
      CH = (int)maxch;
      CH &= ~127;
      if (CH < 128) CH = 128;
    }
  }
  u16* hdn = (u16*)scratch;
  for (int r0 = 0; r0 < BT; r0 += CH) {
    int rows = (BT - r0 < CH) ? (BT - r0) : CH;
    float* oc = out + (size_t)r0 * D_;
    gemm_bf16<2><<<dim3(HD / 128, (rows + 127) / 128), 256, 0, stream>>>(
        ybf + (size_t)r0 * D_, D_, fc1wT, D_, fc1b, nullptr, 0, nullptr, hdn, HD,
        rows, HD, HD, D_, 1.f, 0);
    gemm_bf16<1><<<dim3(D_ / 128, (rows + 127) / 128), 256, 0, stream>>>(
        hdn, HD, fc2wT, HD, fc2b, oc, D_, oc, nullptr, D_,
        rows, D_, D_, HD, 1.f, 0);
  }
}